// Round 10
// baseline (1060.616 us; speedup 1.0000x reference)
//
#include <hip/hip_runtime.h>

// LSTMFeatureExtractor: 2-layer LSTM (H=128) over B=512, T=512, + a*relu(a) head.
// Round 10: per-CU throughput rewrite. 256-thread blocks, 4 waves, each wave
// owns 128 gate rows (8 M-tiles of 16: 4 gates x 2 unit-subtiles). This halves
// the block's per-step LDS fragment traffic (was 8 waves x 8 ds_read_b128 all
// reading the SAME 8KB; now 4 waves) -- LDS pipe was ~45% of step time.
// Weights: 256 VGPR/lane; total ~430 regs -> __launch_bounds__(256,1).
// Producer/consumer pipeline, flags, numerics unchanged from round 7.

typedef _Float16 half8  __attribute__((ext_vector_type(8)));
typedef _Float16 half4_ __attribute__((ext_vector_type(4)));
typedef float    f32x4  __attribute__((ext_vector_type(4)));

#define H_    128
#define T_    512
#define B_    512
#define BCH   16              // batch per block
#define NBG   (B_ / BCH)      // 32 batch groups
#define TCH   8               // timesteps per chunk
#define KPAD  136             // padded LDS row: 272B

#define LOG2E 1.44269504089f

__device__ __forceinline__ float sigm_(float x) {
    return __builtin_amdgcn_rcpf(1.f + __builtin_amdgcn_exp2f(-LOG2E * x));
}
__device__ __forceinline__ float tanh_(float x) {
    return 1.f - 2.f * __builtin_amdgcn_rcpf(1.f + __builtin_amdgcn_exp2f((2.f * LOG2E) * x));
}

__device__ __forceinline__ void lds_barrier() {
    __builtin_amdgcn_sched_barrier(0);
    asm volatile("s_waitcnt lgkmcnt(0)" ::: "memory");
    __builtin_amdgcn_sched_barrier(0);
    __builtin_amdgcn_s_barrier();
    __builtin_amdgcn_sched_barrier(0);
}

#define MFMA16(A, Bv, C) __builtin_amdgcn_mfma_f32_16x16x32_f16((A), (Bv), (C), 0, 0, 0)

// role 0: layer0, x from y (fp32 [b][k][t]), h -> h0ws per step, flag release/chunk.
// role 1: layer1, x from h0ws (flag acquire), fused Wa head + sum a*relu(a) -> out.
__global__ void __launch_bounds__(256, 1)
lstm_fused(const float* __restrict__ y,
           const float* __restrict__ Wih0, const float* __restrict__ Whh0,
           const float* __restrict__ bih0, const float* __restrict__ bhh0,
           const float* __restrict__ Wih1, const float* __restrict__ Whh1,
           const float* __restrict__ bih1, const float* __restrict__ bhh1,
           const float* __restrict__ Wa,  const float* __restrict__ ba,
           _Float16* __restrict__ h0ws,
           int* __restrict__ flags,      // nullptr => no pipeline sync
           float* __restrict__ out,
           int roleBase, int doPipe)
{
    __shared__ _Float16 xbuf[TCH][16][KPAD];
    __shared__ _Float16 hbuf[2][16][KPAD];

    const int tid  = threadIdx.x;
    const int w    = tid >> 6;       // wave 0..3 -> owns units [32w, 32w+32)
    const int l    = tid & 63;
    const int g    = l >> 4;
    const int cl   = l & 15;

    int role, bg;
    if (doPipe) {
        role = (blockIdx.x >> 5) + roleBase;
        bg   = blockIdx.x & 31;
    } else {
        role = roleBase;
        bg   = blockIdx.x & 31;
    }
    const int b0 = bg * BCH;

    // ---- zero hbuf (initial h state) ----
    {
        int* q = (int*)&hbuf[0][0][0];
        for (int i = tid; i < (int)(sizeof(hbuf) / 4); i += 256) q[i] = 0;
    }

    const float* Wih  = role ? Wih1 : Wih0;
    const float* Whh  = role ? Whh1 : Whh0;
    const float* bihp = role ? bih1 : bih0;
    const float* bhhp = role ? bhh1 : bhh0;

    // ---- weight A-fragments: [gate][subtile][ktile], 64 half8 = 256 VGPR ----
    half8 wih[4][2][4], whh[4][2][4];
    #pragma unroll
    for (int gt = 0; gt < 4; ++gt)
        #pragma unroll
        for (int s = 0; s < 2; ++s) {
            const int grow = gt * 128 + w * 32 + s * 16 + cl;   // A row = l&15
            #pragma unroll
            for (int kt = 0; kt < 4; ++kt) {
                const float* pa = Wih + grow * H_ + kt * 32 + g * 8;
                const float* pb = Whh + grow * H_ + kt * 32 + g * 8;
                f32x4 a0 = *(const f32x4*)(pa);
                f32x4 a1 = *(const f32x4*)(pa + 4);
                f32x4 c0 = *(const f32x4*)(pb);
                f32x4 c1 = *(const f32x4*)(pb + 4);
                half8 fa, fb;
                #pragma unroll
                for (int e = 0; e < 4; ++e) {
                    fa[e] = (_Float16)a0[e]; fa[e + 4] = (_Float16)a1[e];
                    fb[e] = (_Float16)c0[e]; fb[e + 4] = (_Float16)c1[e];
                }
                wih[gt][s][kt] = fa; whh[gt][s][kt] = fb;
            }
        }

    // combined bias in C-frag layout: row = gt*128 + w*32 + s*16 + g*4 + r
    f32x4 bias[4][2];
    #pragma unroll
    for (int gt = 0; gt < 4; ++gt)
        #pragma unroll
        for (int s = 0; s < 2; ++s)
            #pragma unroll
            for (int r = 0; r < 4; ++r) {
                const int R = gt * 128 + w * 32 + s * 16 + g * 4 + r;
                bias[gt][s][r] = bihp[R] + bhhp[R];
            }

    // head (role 1): wave w owns out rows [32w, 32w+32): 2 M-tiles
    half8 waf[2][4];
    f32x4 ba4[2];
    f32x4 oacc0 = {0,0,0,0}, oacc1 = {0,0,0,0};
    ba4[0] = f32x4{0,0,0,0}; ba4[1] = f32x4{0,0,0,0};
    if (role == 1) {
        #pragma unroll
        for (int s = 0; s < 2; ++s) {
            const int jrow = w * 32 + s * 16 + cl;
            #pragma unroll
            for (int kt = 0; kt < 4; ++kt) {
                const float* p = Wa + jrow * H_ + kt * 32 + g * 8;
                f32x4 a0 = *(const f32x4*)(p);
                f32x4 a1 = *(const f32x4*)(p + 4);
                half8 f;
                #pragma unroll
                for (int e = 0; e < 4; ++e) { f[e] = (_Float16)a0[e]; f[e + 4] = (_Float16)a1[e]; }
                waf[s][kt] = f;
            }
            #pragma unroll
            for (int r = 0; r < 4; ++r) ba4[s][r] = ba[w * 32 + s * 16 + g * 4 + r];
        }
    }

    float cst[2][4];
    #pragma unroll
    for (int s = 0; s < 2; ++s)
        #pragma unroll
        for (int r = 0; r < 4; ++r) cst[s][r] = 0.f;

    __syncthreads();

    for (int t = 0; t < T_; ++t) {
        const int tb = t & (TCH - 1);
        if (tb == 0) {
            const int c = t >> 3;
            if (role == 0) {
                // stage y[b][k][t..t+7] -> xbuf (f16); 2048 (b,k) rows / 256 thr
                #pragma unroll
                for (int rr = 0; rr < 8; ++rr) {
                    const int q = tid + rr * 256;       // 0..2047
                    const int b = q >> 7, k = q & 127;
                    const float* src = y + ((size_t)((b0 + b) * H_ + k)) * T_ + t;
                    f32x4 v0 = *(const f32x4*)(src);
                    f32x4 v1 = *(const f32x4*)(src + 4);
                    #pragma unroll
                    for (int e = 0; e < 4; ++e) {
                        xbuf[e][b][k]     = (_Float16)v0[e];
                        xbuf[e + 4][b][k] = (_Float16)v1[e];
                    }
                }
            } else {
                if (doPipe) {
                    if (tid == 0) {
                        while (__hip_atomic_load(&flags[bg], __ATOMIC_ACQUIRE,
                                                 __HIP_MEMORY_SCOPE_AGENT) < c + 1)
                            __builtin_amdgcn_s_sleep(2);
                    }
                    __syncthreads();
                }
                // 128 (b,trow) rows, 2 threads each (64 f16 halves)
                const int r_ = tid >> 1;                 // 0..127
                const int b = r_ >> 3, trow = r_ & 7;
                const int u0 = (tid & 1) * 64;
                const _Float16* src =
                    h0ws + ((size_t)(b0 + b) * T_ + (t + trow)) * H_ + u0;
                #pragma unroll
                for (int e = 0; e < 8; ++e) {
                    half8 v = *(const half8*)(src + e * 8);
                    *(half8*)&xbuf[trow][b][u0 + e * 8] = v;
                }
            }
            lds_barrier();
        }

        const int rd = (t ^ 1) & 1;
        const int wr = t & 1;

        half8 xf[4], hf[4];
        #pragma unroll
        for (int kt = 0; kt < 4; ++kt) {
            const int ko = kt * 32 + g * 8;
            xf[kt] = *(const half8*)&xbuf[tb][cl][ko];
            hf[kt] = *(const half8*)&hbuf[rd][cl][ko];
        }

        // 8 independent accumulator chains (one per M-tile), 8 MFMAs deep
        f32x4 acc[4][2];
        #pragma unroll
        for (int gt = 0; gt < 4; ++gt)
            #pragma unroll
            for (int s = 0; s < 2; ++s) acc[gt][s] = bias[gt][s];
        #pragma unroll
        for (int kt = 0; kt < 4; ++kt) {
            #pragma unroll
            for (int gt = 0; gt < 4; ++gt) {
                #pragma unroll
                for (int s = 0; s < 2; ++s) {
                    acc[gt][s] = MFMA16(wih[gt][s][kt], xf[kt], acc[gt][s]);
                    acc[gt][s] = MFMA16(whh[gt][s][kt], hf[kt], acc[gt][s]);
                }
            }
        }

        if (role == 1 && t > 0) {   // head term for h1(t-1), hf already loaded
            f32x4 a0 = ba4[0], a1 = ba4[1];
            #pragma unroll
            for (int kt = 0; kt < 4; ++kt) {
                a0 = MFMA16(waf[0][kt], hf[kt], a0);
                a1 = MFMA16(waf[1][kt], hf[kt], a1);
            }
            #pragma unroll
            for (int r = 0; r < 4; ++r) {
                oacc0[r] += a0[r] * fmaxf(a0[r], 0.f);
                oacc1[r] += a1[r] * fmaxf(a1[r], 0.f);
            }
        }

        // lane-local nonlinearity: units u = w*32 + s*16 + g*4 + r, batch b0+cl
        #pragma unroll
        for (int s = 0; s < 2; ++s) {
            half4_ h4;
            #pragma unroll
            for (int r = 0; r < 4; ++r) {
                const float is  = sigm_(acc[0][s][r]);
                const float fs  = sigm_(acc[1][s][r]);
                const float gt_ = tanh_(acc[2][s][r]);
                const float os  = sigm_(acc[3][s][r]);
                cst[s][r] = fs * cst[s][r] + is * gt_;
                h4[r] = (_Float16)(os * tanh_(cst[s][r]));
            }
            const int u0 = w * 32 + s * 16 + g * 4;
            *(half4_*)&hbuf[wr][cl][u0] = h4;
            if (role == 0) {
                *(half4_*)&h0ws[((size_t)(b0 + cl) * T_ + t) * H_ + u0] = h4;
            }
        }

        if (tb == TCH - 1) {
            __syncthreads();
            if (role == 0 && doPipe) {
                if (tid == 0)
                    __hip_atomic_store(&flags[bg], (t >> 3) + 1, __ATOMIC_RELEASE,
                                       __HIP_MEMORY_SCOPE_AGENT);
            }
        } else {
            lds_barrier();
        }
    }

    if (role == 1) {
        // final head term for h1(T-1) in hbuf[1]
        half8 hfv[4];
        #pragma unroll
        for (int kt = 0; kt < 4; ++kt)
            hfv[kt] = *(const half8*)&hbuf[1][cl][kt * 32 + g * 8];
        f32x4 a0 = ba4[0], a1 = ba4[1];
        #pragma unroll
        for (int kt = 0; kt < 4; ++kt) {
            a0 = MFMA16(waf[0][kt], hfv[kt], a0);
            a1 = MFMA16(waf[1][kt], hfv[kt], a1);
        }
        #pragma unroll
        for (int r = 0; r < 4; ++r) {
            oacc0[r] += a0[r] * fmaxf(a0[r], 0.f);
            oacc1[r] += a1[r] * fmaxf(a1[r], 0.f);
        }
        *(f32x4*)&out[(size_t)(b0 + cl) * H_ + w * 32 + 0 * 16 + g * 4] = oacc0;
        *(f32x4*)&out[(size_t)(b0 + cl) * H_ + w * 32 + 1 * 16 + g * 4] = oacc1;
    }
}

extern "C" void kernel_launch(void* const* d_in, const int* in_sizes, int n_in,
                              void* d_out, int out_size, void* d_ws, size_t ws_size,
                              hipStream_t stream) {
    const float* y    = (const float*)d_in[0];
    const float* Wih0 = (const float*)d_in[1];
    const float* Whh0 = (const float*)d_in[2];
    const float* bih0 = (const float*)d_in[3];
    const float* bhh0 = (const float*)d_in[4];
    const float* Wih1 = (const float*)d_in[5];
    const float* Whh1 = (const float*)d_in[6];
    const float* bih1 = (const float*)d_in[7];
    const float* bhh1 = (const float*)d_in[8];
    const float* Wa   = (const float*)d_in[9];
    const float* ba   = (const float*)d_in[10];
    float* out = (float*)d_out;

    const size_t H0_BYTES = (size_t)B_ * T_ * H_ * sizeof(_Float16); // 64 MiB
    _Float16* h0ws = (_Float16*)d_ws;

    if (ws_size >= H0_BYTES + 512) {
        int* flags = (int*)((char*)d_ws + H0_BYTES);
        hipMemsetAsync(flags, 0, 512, stream);
        lstm_fused<<<2 * NBG, 256, 0, stream>>>(y, Wih0, Whh0, bih0, bhh0,
                                                Wih1, Whh1, bih1, bhh1, Wa, ba,
                                                h0ws, flags, out, 0, 1);
    } else {
        lstm_fused<<<NBG, 256, 0, stream>>>(y, Wih0, Whh0, bih0, bhh0,
                                            Wih1, Whh1, bih1, bhh1, Wa, ba,
                                            h0ws, nullptr, out, 0, 0);
        lstm_fused<<<NBG, 256, 0, stream>>>(y, Wih0, Whh0, bih0, bhh0,
                                            Wih1, Whh1, bih1, bhh1, Wa, ba,
                                            h0ws, nullptr, out, 1, 0);
    }
}

// Round 11
// 931.048 us; speedup vs baseline: 1.1392x; 1.1392x over previous
//
#include <hip/hip_runtime.h>

// LSTMFeatureExtractor: 2-layer LSTM (H=128) over B=512, T=512, + a*relu(a) head.
// Round 11: 4-stage chunk-pipelined dataflow, one launch, 128 blocks x 512 thr.
//   P0 (role 0): stage y chunk (t-major->k-major transpose, OFF the chain) and
//                compute gpre0 = bias0 + x@Wih0^T into a 4-deep f32 ring (ws),
//                stored in exact MFMA C-fragment lane order.
//   S0 (role 1): recurrence layer 0: per step acc = gpre0_seed + h@Whh0^T
//                (16 MFMAs, 4 ds_read_b128, seeds prefetched 2 steps ahead),
//                nonlinearity, h -> hbuf + h0 ring (2-deep).
//   P1 (role 2): gpre1 = bias1 + h0@Wih1^T per chunk into a 2-deep ring.
//   S2 (role 3): recurrence layer 1 + fused Wa head + sum a*relu(a) -> out.
// Flags: fg0 (P0->S0), fh0 (S0->P1), fg1 (P1->S2), fs2 (S2->P1 ring ack).
// Ring safety: P0(c) waits fh0>=c-3; S0(c) waits fg0>=c+1 & fg1>=c-1;
//              P1(c) waits fh0>=c+1 & fs2>=c-1; S2(c) waits fg1>=c+1.

typedef _Float16 half8  __attribute__((ext_vector_type(8)));
typedef _Float16 half4_ __attribute__((ext_vector_type(4)));
typedef float    f32x4  __attribute__((ext_vector_type(4)));

#define H_    128
#define T_    512
#define B_    512
#define BCH   16
#define NBG   32
#define NCH   64              // chunks of 8 steps
#define KPAD  136
#define R0    4               // gpre0 ring depth
#define R1    2               // gpre1 ring depth
#define RH    2               // h0 ring depth
#define CHF   (8 * 32 * 64 * 4)   // floats per gpre chunk slot (65536)
#define H0CH  (8 * 16 * 128)      // halves per h0 chunk slot

#define LOG2E 1.44269504089f

__device__ __forceinline__ float sigm_(float x) {
    return __builtin_amdgcn_rcpf(1.f + __builtin_amdgcn_exp2f(-LOG2E * x));
}
__device__ __forceinline__ float tanh_(float x) {
    return 1.f - 2.f * __builtin_amdgcn_rcpf(1.f + __builtin_amdgcn_exp2f((2.f * LOG2E) * x));
}

__device__ __forceinline__ void lds_barrier() {
    __builtin_amdgcn_sched_barrier(0);
    asm volatile("s_waitcnt lgkmcnt(0)" ::: "memory");
    __builtin_amdgcn_sched_barrier(0);
    __builtin_amdgcn_s_barrier();
    __builtin_amdgcn_sched_barrier(0);
}

__device__ __forceinline__ int fwait(const int* p, int tgt) {
    int v;
    while ((v = __hip_atomic_load(p, __ATOMIC_ACQUIRE, __HIP_MEMORY_SCOPE_AGENT)) < tgt)
        __builtin_amdgcn_s_sleep(2);
    return v;
}
__device__ __forceinline__ void frel(int* p, int v) {
    __hip_atomic_store(p, v, __ATOMIC_RELEASE, __HIP_MEMORY_SCOPE_AGENT);
}

#define MFMA16(A, Bv, C) __builtin_amdgcn_mfma_f32_16x16x32_f16((A), (Bv), (C), 0, 0, 0)

__global__ void __launch_bounds__(512)
lstm_pipe(const float* __restrict__ y,
          const float* __restrict__ Wih0, const float* __restrict__ Whh0,
          const float* __restrict__ bih0, const float* __restrict__ bhh0,
          const float* __restrict__ Wih1, const float* __restrict__ Whh1,
          const float* __restrict__ bih1, const float* __restrict__ bhh1,
          const float* __restrict__ Wa,  const float* __restrict__ ba,
          float* __restrict__ gp0, float* __restrict__ gp1,
          _Float16* __restrict__ h0r, int* __restrict__ flags,
          float* __restrict__ out)
{
    __shared__ _Float16 xbuf[8][16][KPAD];
    __shared__ _Float16 hbuf[2][16][KPAD];

    const int tid = threadIdx.x;
    const int w   = tid >> 6;
    const int l   = tid & 63;
    const int g   = l >> 4;
    const int cl  = l & 15;
    const int role = blockIdx.x & 3;      // 0=P0 1=S0 2=P1 3=S2
    const int bg   = blockIdx.x >> 2;
    const int b0   = bg * BCH;

    int* fg0 = flags;
    int* fh0 = flags + 32;
    int* fg1 = flags + 64;
    int* fs2 = flags + 96;

    { // zero hbuf (S roles need h=0 init; harmless for P)
        int* q = (int*)&hbuf[0][0][0];
        for (int i = tid; i < (int)(sizeof(hbuf) / 4); i += 512) q[i] = 0;
    }

    if (role == 0 || role == 2) {
        // ======================= PROJECTION ROLES =======================
        const int isP1 = (role == 2);
        const float* Wih  = isP1 ? Wih1 : Wih0;
        const float* bihp = isP1 ? bih1 : bih0;
        const float* bhhp = isP1 ? bhh1 : bhh0;

        half8 wf[4][4];
        #pragma unroll
        for (int gt = 0; gt < 4; ++gt) {
            const int grow = gt * 128 + w * 16 + cl;
            #pragma unroll
            for (int kt = 0; kt < 4; ++kt) {
                const float* pa = Wih + grow * H_ + kt * 32 + g * 8;
                f32x4 a0 = *(const f32x4*)(pa);
                f32x4 a1 = *(const f32x4*)(pa + 4);
                half8 fa;
                #pragma unroll
                for (int e = 0; e < 4; ++e) { fa[e] = (_Float16)a0[e]; fa[e + 4] = (_Float16)a1[e]; }
                wf[gt][kt] = fa;
            }
        }
        f32x4 bias[4];
        #pragma unroll
        for (int gt = 0; gt < 4; ++gt)
            #pragma unroll
            for (int r = 0; r < 4; ++r) {
                const int R = gt * 128 + w * 16 + g * 4 + r;
                bias[gt][r] = bihp[R] + bhhp[R];
            }

        float* gpo = isP1 ? gp1 : gp0;
        const int ring = isP1 ? R1 : R0;
        __syncthreads();

        for (int c = 0; c < NCH; ++c) {
            if (tid == 0) {
                if (!isP1) {
                    if (c >= R0) fwait(&fh0[bg], c - 3);   // gpre0 slot free
                } else {
                    fwait(&fh0[bg], c + 1);                // h0 chunk c ready
                    if (c >= R1) fwait(&fs2[bg], c - 1);   // gpre1 slot free
                }
            }
            __syncthreads();

            if (!isP1) {
                // stage y[b][k][c*8 .. +8) -> xbuf (f16), transpose via scalar writes
                #pragma unroll
                for (int rr = 0; rr < 4; ++rr) {
                    const int q = tid + rr * 512;
                    const int b = q >> 7, k = q & 127;
                    const float* src = y + ((size_t)((b0 + b) * H_ + k)) * T_ + c * 8;
                    f32x4 v0 = *(const f32x4*)(src);
                    f32x4 v1 = *(const f32x4*)(src + 4);
                    #pragma unroll
                    for (int e = 0; e < 4; ++e) {
                        xbuf[e][b][k]     = (_Float16)v0[e];
                        xbuf[e + 4][b][k] = (_Float16)v1[e];
                    }
                }
            } else {
                // stage h0 ring slot -> xbuf (coalesced half8)
                const _Float16* sb = h0r + ((size_t)bg * RH + (c & 1)) * H0CH;
                const int pq = tid >> 2;
                const int b = pq >> 3, trow = pq & 7;
                const int u0 = (tid & 3) * 32;
                const _Float16* src = sb + (trow * 16 + b) * 128 + u0;
                #pragma unroll
                for (int e = 0; e < 4; ++e) {
                    half8 v = *(const half8*)(src + e * 8);
                    *(half8*)&xbuf[trow][b][u0 + e * 8] = v;
                }
            }
            lds_barrier();

            // GEMM: 8 steps x 4 gate-tiles, store in C-frag lane order
            float* dst = gpo + ((size_t)bg * ring + (c % ring)) * CHF;
            for (int s = 0; s < 8; ++s) {
                half8 xf[4];
                #pragma unroll
                for (int kt = 0; kt < 4; ++kt)
                    xf[kt] = *(const half8*)&xbuf[s][cl][kt * 32 + g * 8];
                #pragma unroll
                for (int gt = 0; gt < 4; ++gt) {
                    f32x4 acc = bias[gt];
                    #pragma unroll
                    for (int kt = 0; kt < 4; ++kt)
                        acc = MFMA16(wf[gt][kt], xf[kt], acc);
                    *(f32x4*)(dst + ((size_t)((s * 32 + gt * 8 + w) * 64 + l)) * 4) = acc;
                }
            }
            __syncthreads();   // drains vmcnt -> stores visible before release
            if (tid == 0) frel(isP1 ? &fg1[bg] : &fg0[bg], c + 1);
        }
    } else {
        // ======================= RECURRENCE ROLES =======================
        const int isS2 = (role == 3);
        const float* Whh = isS2 ? Whh1 : Whh0;

        half8 whh[4][4];
        #pragma unroll
        for (int gt = 0; gt < 4; ++gt) {
            const int grow = gt * 128 + w * 16 + cl;
            #pragma unroll
            for (int kt = 0; kt < 4; ++kt) {
                const float* pb = Whh + grow * H_ + kt * 32 + g * 8;
                f32x4 c0 = *(const f32x4*)(pb);
                f32x4 c1 = *(const f32x4*)(pb + 4);
                half8 fb;
                #pragma unroll
                for (int e = 0; e < 4; ++e) { fb[e] = (_Float16)c0[e]; fb[e + 4] = (_Float16)c1[e]; }
                whh[gt][kt] = fb;
            }
        }

        half8 waf[4];
        f32x4 ba4  = {0.f, 0.f, 0.f, 0.f};
        f32x4 oacc = {0.f, 0.f, 0.f, 0.f};
        if (isS2) {
            #pragma unroll
            for (int kt = 0; kt < 4; ++kt) {
                const float* p = Wa + (w * 16 + cl) * H_ + kt * 32 + g * 8;
                f32x4 a0 = *(const f32x4*)(p);
                f32x4 a1 = *(const f32x4*)(p + 4);
                half8 f;
                #pragma unroll
                for (int e = 0; e < 4; ++e) { f[e] = (_Float16)a0[e]; f[e + 4] = (_Float16)a1[e]; }
                waf[kt] = f;
            }
            #pragma unroll
            for (int r = 0; r < 4; ++r) ba4[r] = ba[w * 16 + g * 4 + r];
        }

        const float* gps = isS2 ? gp1 : gp0;
        const int ring = isS2 ? R1 : R0;
        float cst[4] = {0.f, 0.f, 0.f, 0.f};
        __syncthreads();

        for (int c = 0; c < NCH; ++c) {
            if (tid == 0) {
                if (!isS2) {
                    fwait(&fg0[bg], c + 1);                // gpre0 chunk ready
                    if (c >= RH) fwait(&fg1[bg], c - 1);   // h0 slot free
                } else {
                    fwait(&fg1[bg], c + 1);                // gpre1 chunk ready
                }
            }
            __syncthreads();

            const float* gpc = gps + ((size_t)bg * ring + (c % ring)) * CHF
                             + (size_t)(w * 64 + l) * 4;
            // seed prefetch for s=0,1
            f32x4 sd[2][4];
            #pragma unroll
            for (int gt = 0; gt < 4; ++gt)
                sd[0][gt] = *(const f32x4*)(gpc + (size_t)((0 * 32 + gt * 8) * 64) * 4);
            #pragma unroll
            for (int gt = 0; gt < 4; ++gt)
                sd[1][gt] = *(const f32x4*)(gpc + (size_t)((1 * 32 + gt * 8) * 64) * 4);

            #pragma unroll
            for (int s = 0; s < 8; ++s) {
                const int rd = (s ^ 1) & 1;    // t parity: c*8 even -> t&1 == s&1
                const int wr = s & 1;

                half8 hf[4];
                #pragma unroll
                for (int kt = 0; kt < 4; ++kt)
                    hf[kt] = *(const half8*)&hbuf[rd][cl][kt * 32 + g * 8];

                f32x4 a0 = sd[s & 1][0], a1 = sd[s & 1][1],
                      a2 = sd[s & 1][2], a3 = sd[s & 1][3];
                if (s + 2 < 8) {   // prefetch seeds for step s+2 (2-step distance)
                    #pragma unroll
                    for (int gt = 0; gt < 4; ++gt)
                        sd[s & 1][gt] =
                            *(const f32x4*)(gpc + (size_t)(((s + 2) * 32 + gt * 8) * 64) * 4);
                }

                #pragma unroll
                for (int kt = 0; kt < 4; ++kt) {
                    a0 = MFMA16(whh[0][kt], hf[kt], a0);
                    a1 = MFMA16(whh[1][kt], hf[kt], a1);
                    a2 = MFMA16(whh[2][kt], hf[kt], a2);
                    a3 = MFMA16(whh[3][kt], hf[kt], a3);
                }

                if (isS2 && !(c == 0 && s == 0)) {   // head for h1(t-1)
                    f32x4 aacc = ba4;
                    #pragma unroll
                    for (int kt = 0; kt < 4; ++kt) aacc = MFMA16(waf[kt], hf[kt], aacc);
                    #pragma unroll
                    for (int r = 0; r < 4; ++r) {
                        const float a = aacc[r];
                        oacc[r] += a * fmaxf(a, 0.f);
                    }
                }

                half4_ h4;
                #pragma unroll
                for (int r = 0; r < 4; ++r) {
                    const float is  = sigm_(a0[r]);
                    const float fs  = sigm_(a1[r]);
                    const float gt_ = tanh_(a2[r]);
                    const float os  = sigm_(a3[r]);
                    cst[r] = fs * cst[r] + is * gt_;
                    h4[r] = (_Float16)(os * tanh_(cst[r]));
                }
                const int u0 = w * 16 + g * 4;
                *(half4_*)&hbuf[wr][cl][u0] = h4;
                if (!isS2) {
                    _Float16* hd = h0r + ((size_t)bg * RH + (c & 1)) * H0CH
                                 + (s * 16 + cl) * 128 + u0;
                    *(half4_*)hd = h4;
                }

                if (s < 7) {
                    lds_barrier();
                } else {
                    __syncthreads();   // drain h0r stores (S0) before release
                    if (tid == 0) frel(isS2 ? &fs2[bg] : &fh0[bg], c + 1);
                }
            }
        }

        if (isS2) {
            // final head term for h1(T-1): t=511 -> written to hbuf[1]
            half8 hfv[4];
            #pragma unroll
            for (int kt = 0; kt < 4; ++kt)
                hfv[kt] = *(const half8*)&hbuf[1][cl][kt * 32 + g * 8];
            f32x4 aacc = ba4;
            #pragma unroll
            for (int kt = 0; kt < 4; ++kt) aacc = MFMA16(waf[kt], hfv[kt], aacc);
            #pragma unroll
            for (int r = 0; r < 4; ++r) {
                const float a = aacc[r];
                oacc[r] += a * fmaxf(a, 0.f);
            }
            *(f32x4*)&out[(size_t)(b0 + cl) * H_ + w * 16 + g * 4] = oacc;
        }
    }
}

extern "C" void kernel_launch(void* const* d_in, const int* in_sizes, int n_in,
                              void* d_out, int out_size, void* d_ws, size_t ws_size,
                              hipStream_t stream) {
    const float* y    = (const float*)d_in[0];
    const float* Wih0 = (const float*)d_in[1];
    const float* Whh0 = (const float*)d_in[2];
    const float* bih0 = (const float*)d_in[3];
    const float* bhh0 = (const float*)d_in[4];
    const float* Wih1 = (const float*)d_in[5];
    const float* Whh1 = (const float*)d_in[6];
    const float* bih1 = (const float*)d_in[7];
    const float* bhh1 = (const float*)d_in[8];
    const float* Wa   = (const float*)d_in[9];
    const float* ba   = (const float*)d_in[10];
    float* out = (float*)d_out;

    const size_t GP0_BYTES = (size_t)NBG * R0 * CHF * 4;          // 32 MiB
    const size_t GP1_BYTES = (size_t)NBG * R1 * CHF * 4;          // 16 MiB
    const size_t H0R_BYTES = (size_t)NBG * RH * H0CH * 2;         // 2 MiB
    char* p = (char*)d_ws;
    float*     gp0   = (float*)p;                 p += GP0_BYTES;
    float*     gp1   = (float*)p;                 p += GP1_BYTES;
    _Float16*  h0r   = (_Float16*)p;              p += H0R_BYTES;
    int*       flags = (int*)p;

    hipMemsetAsync(flags, 0, 512, stream);
    lstm_pipe<<<4 * NBG, 512, 0, stream>>>(y, Wih0, Whh0, bih0, bhh0,
                                           Wih1, Whh1, bih1, bhh1, Wa, ba,
                                           gp0, gp1, h0r, flags, out);
}

// Round 12
// 806.252 us; speedup vs baseline: 1.3155x; 1.1548x over previous
//
#include <hip/hip_runtime.h>

// LSTMFeatureExtractor: 2-layer LSTM (H=128) over B=512, T=512, + a*relu(a) head.
// Round 12: 3-role pipeline, 96 blocks x 512 thr.
//  P0 (role 0): seeds0 = bias0 + x@Wih0^T per 8-step chunk into a 4-deep f16
//               ring, stored per-consumer-thread ([s][gt][tid][4]): coalesced.
//  S0 (role 1): light recurrence layer 0: acc = cvt(seed) + h@Whh0^T
//               (16 MFMAs, 4 ds_read, no staging), nonlin, h -> h0 ring (4-deep).
//  S1 (role 2): round-7 consumer VERBATIM work: stages h0 chunk, ih+hh+head
//               MFMAs, nonlin, a*relu(a) accumulation -> out. (measured 516us solo)
// Flags: fg0 P0->S0 (seeds ready), fs0 S0->P0 (seed slot credit),
//        fh0 S0->S1 (h0 ready),    fs1 S1->S0 (h0 slot credit).
// P0(c): c>=4 wait fs0>=c-3. S0(c): wait fg0>=c+1, c>=4 wait fs1>=c-3.
// S1(c): wait fh0>=c+1, release fs1 after staging. Single tight handoff S0->S1.

typedef _Float16 half8  __attribute__((ext_vector_type(8)));
typedef _Float16 half4_ __attribute__((ext_vector_type(4)));
typedef float    f32x4  __attribute__((ext_vector_type(4)));

#define H_    128
#define T_    512
#define B_    512
#define BCH   16
#define NBG   32
#define NCH   64                  // 8-step chunks
#define KPAD  136
#define RS    4                   // seed ring depth
#define RH    4                   // h0 ring depth
#define SEEDSLOT (8 * 4 * 512 * 4)    // halves per (bg,slot): 65536 (128KB)
#define H0SLOT   (8 * 16 * 128)       // halves per (bg,slot): 16384 (32KB)

#define LOG2E 1.44269504089f

__device__ __forceinline__ float sigm_(float x) {
    return __builtin_amdgcn_rcpf(1.f + __builtin_amdgcn_exp2f(-LOG2E * x));
}
__device__ __forceinline__ float tanh_(float x) {
    return 1.f - 2.f * __builtin_amdgcn_rcpf(1.f + __builtin_amdgcn_exp2f((2.f * LOG2E) * x));
}
__device__ __forceinline__ void lds_barrier() {
    __builtin_amdgcn_sched_barrier(0);
    asm volatile("s_waitcnt lgkmcnt(0)" ::: "memory");
    __builtin_amdgcn_sched_barrier(0);
    __builtin_amdgcn_s_barrier();
    __builtin_amdgcn_sched_barrier(0);
}
__device__ __forceinline__ void fwait(const int* p, int tgt) {
    while (__hip_atomic_load(p, __ATOMIC_ACQUIRE, __HIP_MEMORY_SCOPE_AGENT) < tgt)
        __builtin_amdgcn_s_sleep(2);
}
__device__ __forceinline__ void frel(int* p, int v) {
    __hip_atomic_store(p, v, __ATOMIC_RELEASE, __HIP_MEMORY_SCOPE_AGENT);
}
__device__ __forceinline__ f32x4 cvt4(half4_ h) {
    return f32x4{(float)h[0], (float)h[1], (float)h[2], (float)h[3]};
}
__device__ __forceinline__ half4_ cvh4(f32x4 v) {
    return half4_{(_Float16)v[0], (_Float16)v[1], (_Float16)v[2], (_Float16)v[3]};
}

#define MFMA16(A, Bv, C) __builtin_amdgcn_mfma_f32_16x16x32_f16((A), (Bv), (C), 0, 0, 0)

__global__ void __launch_bounds__(512)
lstm3(const float* __restrict__ y,
      const float* __restrict__ Wih0, const float* __restrict__ Whh0,
      const float* __restrict__ bih0, const float* __restrict__ bhh0,
      const float* __restrict__ Wih1, const float* __restrict__ Whh1,
      const float* __restrict__ bih1, const float* __restrict__ bhh1,
      const float* __restrict__ Wa,  const float* __restrict__ ba,
      _Float16* __restrict__ seeds, _Float16* __restrict__ h0r,
      int* __restrict__ flags, float* __restrict__ out)
{
    __shared__ _Float16 xbuf[8][16][KPAD];
    __shared__ _Float16 hbuf[2][16][KPAD];

    const int tid = threadIdx.x;
    const int w   = tid >> 6;
    const int l   = tid & 63;
    const int g   = l >> 4;
    const int cl  = l & 15;
    const int role = blockIdx.x % 3;     // 0=P0 1=S0 2=S1
    const int bg   = blockIdx.x / 3;
    const int b0   = bg * BCH;

    int* fg0 = flags;        // P0 -> S0: seeds chunk ready
    int* fs0 = flags + 32;   // S0 -> P0: seed slot credit
    int* fh0 = flags + 64;   // S0 -> S1: h0 chunk ready
    int* fs1 = flags + 96;   // S1 -> S0: h0 slot credit

    { // zero hbuf (initial h state for S roles)
        int* q = (int*)&hbuf[0][0][0];
        for (int i = tid; i < (int)(sizeof(hbuf) / 4); i += 512) q[i] = 0;
    }

    if (role == 0) {
        // ====================== P0: layer-0 input projection ======================
        half8 wf[4][4];
        #pragma unroll
        for (int gt = 0; gt < 4; ++gt) {
            const int grow = gt * 128 + w * 16 + cl;
            #pragma unroll
            for (int kt = 0; kt < 4; ++kt) {
                const float* pa = Wih0 + grow * H_ + kt * 32 + g * 8;
                f32x4 a0 = *(const f32x4*)(pa);
                f32x4 a1 = *(const f32x4*)(pa + 4);
                half8 fa;
                #pragma unroll
                for (int e = 0; e < 4; ++e) { fa[e] = (_Float16)a0[e]; fa[e + 4] = (_Float16)a1[e]; }
                wf[gt][kt] = fa;
            }
        }
        f32x4 bias[4];
        #pragma unroll
        for (int gt = 0; gt < 4; ++gt)
            #pragma unroll
            for (int r = 0; r < 4; ++r) {
                const int R = gt * 128 + w * 16 + g * 4 + r;
                bias[gt][r] = bih0[R] + bhh0[R];
            }
        __syncthreads();

        for (int c = 0; c < NCH; ++c) {
            if (tid == 0 && c >= RS) fwait(&fs0[bg], c - (RS - 1));
            __syncthreads();

            // stage y[b][k][c*8..+8) -> xbuf (f16)
            #pragma unroll
            for (int rr = 0; rr < 4; ++rr) {
                const int q = tid + rr * 512;
                const int b = q >> 7, k = q & 127;
                const float* src = y + ((size_t)((b0 + b) * H_ + k)) * T_ + c * 8;
                f32x4 v0 = *(const f32x4*)(src);
                f32x4 v1 = *(const f32x4*)(src + 4);
                #pragma unroll
                for (int e = 0; e < 4; ++e) {
                    xbuf[e][b][k]     = (_Float16)v0[e];
                    xbuf[e + 4][b][k] = (_Float16)v1[e];
                }
            }
            lds_barrier();

            _Float16* sb = seeds + (size_t)(bg * RS + (c & (RS - 1))) * SEEDSLOT;
            for (int s = 0; s < 8; ++s) {
                half8 xf[4];
                #pragma unroll
                for (int kt = 0; kt < 4; ++kt)
                    xf[kt] = *(const half8*)&xbuf[s][cl][kt * 32 + g * 8];
                #pragma unroll
                for (int gt = 0; gt < 4; ++gt) {
                    f32x4 acc = bias[gt];
                    #pragma unroll
                    for (int kt = 0; kt < 4; ++kt)
                        acc = MFMA16(wf[gt][kt], xf[kt], acc);
                    // per-consumer-thread layout: [(s*4+gt)*512 + tid]*4 halves
                    *(half4_*)(sb + ((size_t)(s * 4 + gt) * 512 + tid) * 4) = cvh4(acc);
                }
            }
            __syncthreads();                 // drain seed stores (vmcnt)
            if (tid == 0) frel(&fg0[bg], c + 1);
        }
    } else if (role == 1) {
        // ====================== S0: light recurrence, layer 0 ======================
        half8 whh[4][4];
        #pragma unroll
        for (int gt = 0; gt < 4; ++gt) {
            const int grow = gt * 128 + w * 16 + cl;
            #pragma unroll
            for (int kt = 0; kt < 4; ++kt) {
                const float* pb = Whh0 + grow * H_ + kt * 32 + g * 8;
                f32x4 c0 = *(const f32x4*)(pb);
                f32x4 c1 = *(const f32x4*)(pb + 4);
                half8 fb;
                #pragma unroll
                for (int e = 0; e < 4; ++e) { fb[e] = (_Float16)c0[e]; fb[e + 4] = (_Float16)c1[e]; }
                whh[gt][kt] = fb;
            }
        }
        float cst[4] = {0.f, 0.f, 0.f, 0.f};
        __syncthreads();

        for (int c = 0; c < NCH; ++c) {
            if (tid == 0) {
                fwait(&fg0[bg], c + 1);                       // seeds ready
                if (c >= RH) fwait(&fs1[bg], c - (RH - 1));   // h0 slot free
            }
            __syncthreads();

            const _Float16* sb = seeds + (size_t)(bg * RS + (c & (RS - 1))) * SEEDSLOT
                               + (size_t)tid * 4;
            _Float16* hb = h0r + (size_t)(bg * RH + (c & (RH - 1))) * H0SLOT;

            half4_ sd[2][4];
            #pragma unroll
            for (int gt = 0; gt < 4; ++gt)
                sd[0][gt] = *(const half4_*)(sb + (size_t)(0 * 4 + gt) * 2048);
            #pragma unroll
            for (int gt = 0; gt < 4; ++gt)
                sd[1][gt] = *(const half4_*)(sb + (size_t)(1 * 4 + gt) * 2048);

            #pragma unroll
            for (int s = 0; s < 8; ++s) {
                const int rd = (s ^ 1) & 1;
                const int wr = s & 1;

                half8 hf[4];
                #pragma unroll
                for (int kt = 0; kt < 4; ++kt)
                    hf[kt] = *(const half8*)&hbuf[rd][cl][kt * 32 + g * 8];

                f32x4 a0 = cvt4(sd[s & 1][0]);
                f32x4 a1 = cvt4(sd[s & 1][1]);
                f32x4 a2 = cvt4(sd[s & 1][2]);
                f32x4 a3 = cvt4(sd[s & 1][3]);
                if (s + 2 < 8) {
                    #pragma unroll
                    for (int gt = 0; gt < 4; ++gt)
                        sd[s & 1][gt] =
                            *(const half4_*)(sb + (size_t)((s + 2) * 4 + gt) * 2048);
                }

                #pragma unroll
                for (int kt = 0; kt < 4; ++kt) {
                    a0 = MFMA16(whh[0][kt], hf[kt], a0);
                    a1 = MFMA16(whh[1][kt], hf[kt], a1);
                    a2 = MFMA16(whh[2][kt], hf[kt], a2);
                    a3 = MFMA16(whh[3][kt], hf[kt], a3);
                }

                half4_ h4;
                #pragma unroll
                for (int r = 0; r < 4; ++r) {
                    const float is  = sigm_(a0[r]);
                    const float fs  = sigm_(a1[r]);
                    const float gt_ = tanh_(a2[r]);
                    const float os  = sigm_(a3[r]);
                    cst[r] = fs * cst[r] + is * gt_;
                    h4[r] = (_Float16)(os * tanh_(cst[r]));
                }
                const int u0 = w * 16 + g * 4;
                *(half4_*)&hbuf[wr][cl][u0] = h4;
                *(half4_*)(hb + (s * 16 + cl) * 128 + u0) = h4;

                if (s < 7) {
                    lds_barrier();
                } else {
                    __syncthreads();            // drain h0 stores + seed loads
                    if (tid == 0) {
                        frel(&fh0[bg], c + 1);  // h0 chunk ready for S1
                        frel(&fs0[bg], c + 1);  // seed slot free for P0
                    }
                }
            }
        }
    } else {
        // ====================== S1: layer-1 recurrence + head (r7 consumer) ======================
        half8 wihf[4][4], whhf[4][4];
        #pragma unroll
        for (int gt = 0; gt < 4; ++gt) {
            const int grow = gt * 128 + w * 16 + cl;
            #pragma unroll
            for (int kt = 0; kt < 4; ++kt) {
                const float* pa = Wih1 + grow * H_ + kt * 32 + g * 8;
                const float* pb = Whh1 + grow * H_ + kt * 32 + g * 8;
                f32x4 a0 = *(const f32x4*)(pa);
                f32x4 a1 = *(const f32x4*)(pa + 4);
                f32x4 c0 = *(const f32x4*)(pb);
                f32x4 c1 = *(const f32x4*)(pb + 4);
                half8 fa, fb;
                #pragma unroll
                for (int e = 0; e < 4; ++e) {
                    fa[e] = (_Float16)a0[e]; fa[e + 4] = (_Float16)a1[e];
                    fb[e] = (_Float16)c0[e]; fb[e + 4] = (_Float16)c1[e];
                }
                wihf[gt][kt] = fa; whhf[gt][kt] = fb;
            }
        }
        f32x4 bias[4];
        #pragma unroll
        for (int gt = 0; gt < 4; ++gt)
            #pragma unroll
            for (int r = 0; r < 4; ++r) {
                const int R = gt * 128 + w * 16 + g * 4 + r;
                bias[gt][r] = bih1[R] + bhh1[R];
            }
        half8 waf[4];
        f32x4 ba4  = {0.f, 0.f, 0.f, 0.f};
        f32x4 oacc = {0.f, 0.f, 0.f, 0.f};
        #pragma unroll
        for (int kt = 0; kt < 4; ++kt) {
            const float* p = Wa + (w * 16 + cl) * H_ + kt * 32 + g * 8;
            f32x4 a0 = *(const f32x4*)(p);
            f32x4 a1 = *(const f32x4*)(p + 4);
            half8 f;
            #pragma unroll
            for (int e = 0; e < 4; ++e) { f[e] = (_Float16)a0[e]; f[e + 4] = (_Float16)a1[e]; }
            waf[kt] = f;
        }
        #pragma unroll
        for (int r = 0; r < 4; ++r) ba4[r] = ba[w * 16 + g * 4 + r];

        float cst[4] = {0.f, 0.f, 0.f, 0.f};
        __syncthreads();

        for (int t = 0; t < T_; ++t) {
            const int tb = t & 7;
            if (tb == 0) {
                const int c = t >> 3;
                if (tid == 0) fwait(&fh0[bg], c + 1);
                __syncthreads();
                // stage h0 ring slot -> xbuf (coalesced half8)
                const _Float16* sbh = h0r + (size_t)(bg * RH + (c & (RH - 1))) * H0SLOT;
                const int pq = tid >> 2;
                const int b = pq >> 3, trow = pq & 7;
                const int u0 = (tid & 3) * 32;
                const _Float16* src = sbh + (trow * 16 + b) * 128 + u0;
                #pragma unroll
                for (int e = 0; e < 4; ++e) {
                    half8 v = *(const half8*)(src + e * 8);
                    *(half8*)&xbuf[trow][b][u0 + e * 8] = v;
                }
                lds_barrier();
                if (tid == 0) frel(&fs1[bg], c + 1);   // slot consumed
            }

            const int rd = (t ^ 1) & 1;
            const int wr = t & 1;

            f32x4 ai0 = bias[0], ai1 = bias[1], ai2 = bias[2], ai3 = bias[3];
            f32x4 ah0 = {0,0,0,0}, ah1 = {0,0,0,0}, ah2 = {0,0,0,0}, ah3 = {0,0,0,0};
            half8 hf[4];
            #pragma unroll
            for (int kt = 0; kt < 4; ++kt) {
                const int ko = kt * 32 + g * 8;
                const half8 xf = *(const half8*)&xbuf[tb][cl][ko];
                hf[kt]         = *(const half8*)&hbuf[rd][cl][ko];
                ai0 = MFMA16(wihf[0][kt], xf, ai0);
                ai1 = MFMA16(wihf[1][kt], xf, ai1);
                ai2 = MFMA16(wihf[2][kt], xf, ai2);
                ai3 = MFMA16(wihf[3][kt], xf, ai3);
                ah0 = MFMA16(whhf[0][kt], hf[kt], ah0);
                ah1 = MFMA16(whhf[1][kt], hf[kt], ah1);
                ah2 = MFMA16(whhf[2][kt], hf[kt], ah2);
                ah3 = MFMA16(whhf[3][kt], hf[kt], ah3);
            }

            if (t > 0) {   // head term for h1(t-1)
                f32x4 aacc = ba4;
                #pragma unroll
                for (int kt = 0; kt < 4; ++kt) aacc = MFMA16(waf[kt], hf[kt], aacc);
                #pragma unroll
                for (int r = 0; r < 4; ++r) {
                    const float a = aacc[r];
                    oacc[r] += a * fmaxf(a, 0.f);
                }
            }

            half4_ h4;
            #pragma unroll
            for (int r = 0; r < 4; ++r) {
                const float i_ = ai0[r] + ah0[r];
                const float f_ = ai1[r] + ah1[r];
                const float g_ = ai2[r] + ah2[r];
                const float o_ = ai3[r] + ah3[r];
                const float is = sigm_(i_);
                const float fs = sigm_(f_);
                const float gt_ = tanh_(g_);
                const float os = sigm_(o_);
                cst[r] = fs * cst[r] + is * gt_;
                h4[r] = (_Float16)(os * tanh_(cst[r]));
            }
            const int u0 = w * 16 + g * 4;
            *(half4_*)&hbuf[wr][cl][u0] = h4;
            lds_barrier();
        }

        // final head term for h1(T-1) in hbuf[1]
        f32x4 aacc = ba4;
        #pragma unroll
        for (int kt = 0; kt < 4; ++kt) {
            const half8 hfv = *(const half8*)&hbuf[1][cl][kt * 32 + g * 8];
            aacc = MFMA16(waf[kt], hfv, aacc);
        }
        #pragma unroll
        for (int r = 0; r < 4; ++r) {
            const float a = aacc[r];
            oacc[r] += a * fmaxf(a, 0.f);
        }
        *(f32x4*)&out[(size_t)(b0 + cl) * H_ + w * 16 + g * 4] = oacc;
    }
}

extern "C" void kernel_launch(void* const* d_in, const int* in_sizes, int n_in,
                              void* d_out, int out_size, void* d_ws, size_t ws_size,
                              hipStream_t stream) {
    const float* y    = (const float*)d_in[0];
    const float* Wih0 = (const float*)d_in[1];
    const float* Whh0 = (const float*)d_in[2];
    const float* bih0 = (const float*)d_in[3];
    const float* bhh0 = (const float*)d_in[4];
    const float* Wih1 = (const float*)d_in[5];
    const float* Whh1 = (const float*)d_in[6];
    const float* bih1 = (const float*)d_in[7];
    const float* bhh1 = (const float*)d_in[8];
    const float* Wa   = (const float*)d_in[9];
    const float* ba   = (const float*)d_in[10];
    float* out = (float*)d_out;

    const size_t SEED_BYTES = (size_t)NBG * RS * SEEDSLOT * 2;   // 16 MiB
    const size_t H0_BYTES   = (size_t)NBG * RH * H0SLOT * 2;     // 4 MiB
    char* p = (char*)d_ws;
    _Float16* seeds = (_Float16*)p;             p += SEED_BYTES;
    _Float16* h0r   = (_Float16*)p;             p += H0_BYTES;
    int*      flags = (int*)p;

    hipMemsetAsync(flags, 0, 512, stream);
    lstm3<<<3 * NBG, 512, 0, stream>>>(y, Wih0, Whh0, bih0, bhh0,
                                       Wih1, Whh1, bih1, bhh1, Wa, ba,
                                       seeds, h0r, flags, out);
}